// Round 1
// baseline (3173.417 us; speedup 1.0000x reference)
//
#include <hip/hip_runtime.h>
#include <math.h>

#define F_IN 128
#define HDIM 256
#define CDIM 32

// ---------------- degree / norm ----------------
__global__ void k_deg_init(float* deg, int N) {
  int i = blockIdx.x * blockDim.x + threadIdx.x;
  if (i < N) deg[i] = 1.0f;  // self loop
}

__global__ void k_deg_count(const int* __restrict__ ei, float* __restrict__ deg, int E) {
  int e = blockIdx.x * blockDim.x + threadIdx.x;
  if (e < E) atomicAdd(&deg[ei[(size_t)E + e]], 1.0f);
}

__global__ void k_dinv(float* deg, int N) {
  int i = blockIdx.x * blockDim.x + threadIdx.x;
  if (i < N) deg[i] = rsqrtf(deg[i]);
}

// ---------------- layer-1 aggregation (on x, 128 wide) ----------------
__global__ void k_init_aggx(const float* __restrict__ x, const float* __restrict__ dinv,
                            float* __restrict__ agg, int N) {
  int idx = blockIdx.x * blockDim.x + threadIdx.x;  // over N*32 float4
  if (idx >= N * (F_IN / 4)) return;
  int row = idx >> 5;  // 32 float4 per row
  float sc = dinv[row];
  sc *= sc;
  float4 v = ((const float4*)x)[idx];
  v.x *= sc; v.y *= sc; v.z *= sc; v.w *= sc;
  ((float4*)agg)[idx] = v;
}

__global__ void k_scatter1(const float* __restrict__ x, const int* __restrict__ ei,
                           const float* __restrict__ dinv, float* __restrict__ agg, int E) {
  long long idx = (long long)blockIdx.x * blockDim.x + threadIdx.x;
  int e = (int)(idx >> 5);
  if (e >= E) return;
  int lane = (int)(idx & 31);
  int s = ei[e];
  int d = ei[(size_t)E + e];
  float nrm = dinv[s] * dinv[d];
  float4 v = ((const float4*)(x + (size_t)s * F_IN))[lane];
  float* o = agg + (size_t)d * F_IN + lane * 4;
  atomicAdd(o + 0, v.x * nrm);
  atomicAdd(o + 1, v.y * nrm);
  atomicAdd(o + 2, v.z * nrm);
  atomicAdd(o + 3, v.w * nrm);
}

// ---------------- GEMM1: [N,128]x[128,256] + bias, relu ----------------
#define BM 64
#define BN 64
#define BK 32
__global__ __launch_bounds__(256) void k_gemm1(const float* __restrict__ A,
                                               const float* __restrict__ W,
                                               const float* __restrict__ bias,
                                               float* __restrict__ C, int M) {
  __shared__ float As[BM][BK + 1];
  __shared__ float Bs[BK][BN];
  int tid = threadIdx.x;
  int bm = blockIdx.x * BM;
  int bn = blockIdx.y * BN;
  int tr = tid >> 4, tc = tid & 15;
  float acc[4][4] = {{0.f}};
  for (int k0 = 0; k0 < F_IN; k0 += BK) {
#pragma unroll
    for (int i = 0; i < 2; ++i) {
      int f4 = tid + i * 256;      // 512 float4 total
      int row = f4 >> 3, col4 = f4 & 7;
      float4 v = make_float4(0.f, 0.f, 0.f, 0.f);
      if (bm + row < M) v = ((const float4*)(A + (size_t)(bm + row) * F_IN + k0))[col4];
      As[row][col4 * 4 + 0] = v.x;
      As[row][col4 * 4 + 1] = v.y;
      As[row][col4 * 4 + 2] = v.z;
      As[row][col4 * 4 + 3] = v.w;
    }
#pragma unroll
    for (int i = 0; i < 2; ++i) {
      int f4 = tid + i * 256;
      int row = f4 >> 4, n4 = f4 & 15;
      float4 v = ((const float4*)(W + (size_t)(k0 + row) * HDIM + bn))[n4];
      *((float4*)&Bs[row][n4 * 4]) = v;
    }
    __syncthreads();
#pragma unroll
    for (int kk = 0; kk < BK; ++kk) {
      float a[4], b[4];
#pragma unroll
      for (int i = 0; i < 4; ++i) a[i] = As[tr * 4 + i][kk];
#pragma unroll
      for (int j = 0; j < 4; ++j) b[j] = Bs[kk][tc * 4 + j];
#pragma unroll
      for (int i = 0; i < 4; ++i)
#pragma unroll
        for (int j = 0; j < 4; ++j) acc[i][j] += a[i] * b[j];
    }
    __syncthreads();
  }
  float bb[4];
#pragma unroll
  for (int j = 0; j < 4; ++j) bb[j] = bias[bn + tc * 4 + j];
#pragma unroll
  for (int i = 0; i < 4; ++i) {
    int r = bm + tr * 4 + i;
    if (r >= M) continue;
    float4 o;
    o.x = fmaxf(acc[i][0] + bb[0], 0.f);
    o.y = fmaxf(acc[i][1] + bb[1], 0.f);
    o.z = fmaxf(acc[i][2] + bb[2], 0.f);
    o.w = fmaxf(acc[i][3] + bb[3], 0.f);
    *((float4*)(C + (size_t)r * HDIM + bn + tc * 4)) = o;
  }
}

// ---------------- GEMM2: [N,256]x[256,32] (W2 fully in LDS) ----------------
__global__ __launch_bounds__(256) void k_gemm2(const float* __restrict__ H1,
                                               const float* __restrict__ W2,
                                               float* __restrict__ T, int M) {
  __shared__ float Ws[HDIM * CDIM];  // 32 KB
  for (int i = threadIdx.x; i < HDIM * CDIM / 4; i += 256)
    ((float4*)Ws)[i] = ((const float4*)W2)[i];
  __syncthreads();
  int c = threadIdx.x & 31;
  int r0 = blockIdx.x * 64 + (threadIdx.x >> 5) * 8;
  for (int rr = 0; rr < 8; ++rr) {
    int r = r0 + rr;
    if (r >= M) break;
    const float* hrow = H1 + (size_t)r * HDIM;
    float acc = 0.f;
#pragma unroll
    for (int k4 = 0; k4 < HDIM / 4; ++k4) {
      float4 h = ((const float4*)hrow)[k4];
      acc = fmaf(h.x, Ws[(k4 * 4 + 0) * CDIM + c], acc);
      acc = fmaf(h.y, Ws[(k4 * 4 + 1) * CDIM + c], acc);
      acc = fmaf(h.z, Ws[(k4 * 4 + 2) * CDIM + c], acc);
      acc = fmaf(h.w, Ws[(k4 * 4 + 3) * CDIM + c], acc);
    }
    T[(size_t)r * CDIM + c] = acc;
  }
}

// ---------------- layer-2 aggregation (32 wide) + epilogue ----------------
__global__ void k_init_out(const float* __restrict__ t, const float* __restrict__ dinv,
                           const float* __restrict__ b2, float* __restrict__ out, int N) {
  int idx = blockIdx.x * blockDim.x + threadIdx.x;  // N*32
  if (idx >= N * CDIM) return;
  int row = idx >> 5;
  float sc = dinv[row];
  sc *= sc;
  out[idx] = b2[idx & 31] + t[idx] * sc;
}

__global__ void k_scatter2(const float* __restrict__ t, const int* __restrict__ ei,
                           const float* __restrict__ dinv, float* __restrict__ out, int E) {
  long long idx = (long long)blockIdx.x * blockDim.x + threadIdx.x;
  int e = (int)(idx >> 5);
  if (e >= E) return;
  int lane = (int)(idx & 31);
  int s = ei[e];
  int d = ei[(size_t)E + e];
  float nrm = dinv[s] * dinv[d];
  float v = t[(size_t)s * CDIM + lane] * nrm;
  atomicAdd(&out[(size_t)d * CDIM + lane], v);
}

__global__ void k_logsoftmax(float* __restrict__ out, int N) {
  int r = blockIdx.x * blockDim.x + threadIdx.x;
  if (r >= N) return;
  float* p = out + (size_t)r * CDIM;
  float v[CDIM];
#pragma unroll
  for (int i = 0; i < CDIM / 4; ++i) ((float4*)v)[i] = ((float4*)p)[i];
  float m = v[0];
#pragma unroll
  for (int i = 1; i < CDIM; ++i) m = fmaxf(m, v[i]);
  float s = 0.f;
#pragma unroll
  for (int i = 0; i < CDIM; ++i) s += __expf(v[i] - m);
  float ls = m + __logf(s);
#pragma unroll
  for (int i = 0; i < CDIM; ++i) v[i] -= ls;
#pragma unroll
  for (int i = 0; i < CDIM / 4; ++i) ((float4*)p)[i] = ((float4*)v)[i];
}

extern "C" void kernel_launch(void* const* d_in, const int* in_sizes, int n_in,
                              void* d_out, int out_size, void* d_ws, size_t ws_size,
                              hipStream_t stream) {
  const float* x  = (const float*)d_in[0];
  const int*   ei = (const int*)d_in[1];
  const float* W1 = (const float*)d_in[2];
  const float* b1 = (const float*)d_in[3];
  const float* W2 = (const float*)d_in[4];
  const float* b2 = (const float*)d_in[5];
  float* out = (float*)d_out;
  int N = in_sizes[0] / F_IN;
  int E = in_sizes[1] / 2;

  float* ws = (float*)d_ws;
  float* dinv = ws;                              // N floats
  size_t off = ((size_t)N + 255) & ~(size_t)255;
  float* aggx = ws + off;                        // N*128 floats (reused as T: N*32)
  float* h1 = aggx + (size_t)N * F_IN;           // N*256 floats

  k_deg_init<<<(N + 255) / 256, 256, 0, stream>>>(dinv, N);
  k_deg_count<<<(E + 255) / 256, 256, 0, stream>>>(ei, dinv, E);
  k_dinv<<<(N + 255) / 256, 256, 0, stream>>>(dinv, N);

  int n32 = N * 32;
  k_init_aggx<<<(n32 + 255) / 256, 256, 0, stream>>>(x, dinv, aggx, N);
  long long th = (long long)E * 32;
  k_scatter1<<<(int)((th + 255) / 256), 256, 0, stream>>>(x, ei, dinv, aggx, E);

  dim3 g1((N + BM - 1) / BM, HDIM / BN);
  k_gemm1<<<g1, 256, 0, stream>>>(aggx, W1, b1, h1, N);
  k_gemm2<<<(N + 63) / 64, 256, 0, stream>>>(h1, W2, aggx, N);

  k_init_out<<<(n32 + 255) / 256, 256, 0, stream>>>(aggx, dinv, b2, out, N);
  k_scatter2<<<(int)((th + 255) / 256), 256, 0, stream>>>(aggx, ei, dinv, out, E);
  k_logsoftmax<<<(N + 255) / 256, 256, 0, stream>>>(out, N);
}

// Round 2
// 898.146 us; speedup vs baseline: 3.5333x; 3.5333x over previous
//
#include <hip/hip_runtime.h>
#include <math.h>

#define F_IN 128
#define HDIM 256
#define CDIM 32

// ---------------- degree / norm / CSR build ----------------
__global__ void k_cnt_init(int* cnt, int N) {
  int i = blockIdx.x * blockDim.x + threadIdx.x;
  if (i < N) cnt[i] = 0;
}

__global__ void k_deg_count(const int* __restrict__ ei, int* __restrict__ cnt, int E) {
  int e = blockIdx.x * blockDim.x + threadIdx.x;
  if (e < E) atomicAdd(&cnt[ei[(size_t)E + e]], 1);
}

__global__ void k_dinv(const int* __restrict__ cnt, float* __restrict__ dinv, int N) {
  int i = blockIdx.x * blockDim.x + threadIdx.x;
  if (i < N) dinv[i] = rsqrtf((float)cnt[i] + 1.0f);  // +1 self loop
}

// single-workgroup exclusive scan: offs[i] = sum cnt[0..i), offs[N] = total
// also writes cursor[i] = offs[i]
__global__ __launch_bounds__(1024) void k_scan(const int* __restrict__ cnt,
                                               int* __restrict__ offs,
                                               int* __restrict__ cursor, int N) {
  __shared__ int part[1024];
  int tid = threadIdx.x;
  int per = (N + 1023) / 1024;
  int start = tid * per;
  int end = start + per;
  if (end > N) end = N;
  int s = 0;
  for (int i = start; i < end; ++i) s += cnt[i];
  part[tid] = s;
  __syncthreads();
  // Hillis-Steele inclusive scan
  for (int off = 1; off < 1024; off <<= 1) {
    int v = 0;
    if (tid >= off) v = part[tid - off];
    __syncthreads();
    part[tid] += v;
    __syncthreads();
  }
  int run = part[tid] - s;  // exclusive base
  for (int i = start; i < end; ++i) {
    offs[i] = run;
    cursor[i] = run;
    run += cnt[i];
  }
  if (tid == 0) offs[N] = part[1023];
}

__global__ void k_fill(const int* __restrict__ ei, int* __restrict__ cursor,
                       int* __restrict__ srcs, int E) {
  int e = blockIdx.x * blockDim.x + threadIdx.x;
  if (e >= E) return;
  int s = ei[e];
  int d = ei[(size_t)E + e];
  int pos = atomicAdd(&cursor[d], 1);
  srcs[pos] = s;
}

// ---------------- layer-1 aggregation: gather, one wave per dst ----------------
__global__ __launch_bounds__(256) void k_agg1(const float* __restrict__ x,
                                              const int* __restrict__ srcs,
                                              const int* __restrict__ offs,
                                              const float* __restrict__ dinv,
                                              float* __restrict__ agg, int N) {
  int row = (blockIdx.x * 256 + threadIdx.x) >> 6;  // one wave per row
  int lane = threadIdx.x & 63;
  if (row >= N) return;
  float dd = dinv[row];
  const float2* xr = (const float2*)(x + (size_t)row * F_IN);
  float2 v = xr[lane];
  float sc = dd * dd;
  float ax = v.x * sc, ay = v.y * sc;  // self loop
  int beg = offs[row], end = offs[row + 1];
  for (int k = beg; k < end; ++k) {
    int s = srcs[k];
    float nrm = dinv[s] * dd;
    float2 u = ((const float2*)(x + (size_t)s * F_IN))[lane];
    ax = fmaf(u.x, nrm, ax);
    ay = fmaf(u.y, nrm, ay);
  }
  float2 o; o.x = ax; o.y = ay;
  ((float2*)(agg + (size_t)row * F_IN))[lane] = o;
}

// ---------------- GEMM1: [M,128]x[128,256] + bias, relu ----------------
#define BM 64
#define BN 64
#define BK 32
__global__ __launch_bounds__(256) void k_gemm1(const float* __restrict__ A,
                                               const float* __restrict__ W,
                                               const float* __restrict__ bias,
                                               float* __restrict__ C, int M) {
  __shared__ float As[BM][BK + 1];
  __shared__ float Bs[BK][BN];
  int tid = threadIdx.x;
  int bm = blockIdx.x * BM;
  int bn = blockIdx.y * BN;
  int tr = tid >> 4, tc = tid & 15;
  float acc[4][4] = {{0.f}};
  for (int k0 = 0; k0 < F_IN; k0 += BK) {
#pragma unroll
    for (int i = 0; i < 2; ++i) {
      int f4 = tid + i * 256;
      int row = f4 >> 3, col4 = f4 & 7;
      float4 v = make_float4(0.f, 0.f, 0.f, 0.f);
      if (bm + row < M) v = ((const float4*)(A + (size_t)(bm + row) * F_IN + k0))[col4];
      As[row][col4 * 4 + 0] = v.x;
      As[row][col4 * 4 + 1] = v.y;
      As[row][col4 * 4 + 2] = v.z;
      As[row][col4 * 4 + 3] = v.w;
    }
#pragma unroll
    for (int i = 0; i < 2; ++i) {
      int f4 = tid + i * 256;
      int row = f4 >> 4, n4 = f4 & 15;
      float4 v = ((const float4*)(W + (size_t)(k0 + row) * HDIM + bn))[n4];
      *((float4*)&Bs[row][n4 * 4]) = v;
    }
    __syncthreads();
#pragma unroll
    for (int kk = 0; kk < BK; ++kk) {
      float a[4], b[4];
#pragma unroll
      for (int i = 0; i < 4; ++i) a[i] = As[tr * 4 + i][kk];
#pragma unroll
      for (int j = 0; j < 4; ++j) b[j] = Bs[kk][tc * 4 + j];
#pragma unroll
      for (int i = 0; i < 4; ++i)
#pragma unroll
        for (int j = 0; j < 4; ++j) acc[i][j] = fmaf(a[i], b[j], acc[i][j]);
    }
    __syncthreads();
  }
  float bb[4];
#pragma unroll
  for (int j = 0; j < 4; ++j) bb[j] = bias[bn + tc * 4 + j];
#pragma unroll
  for (int i = 0; i < 4; ++i) {
    int r = bm + tr * 4 + i;
    if (r >= M) continue;
    float4 o;
    o.x = fmaxf(acc[i][0] + bb[0], 0.f);
    o.y = fmaxf(acc[i][1] + bb[1], 0.f);
    o.z = fmaxf(acc[i][2] + bb[2], 0.f);
    o.w = fmaxf(acc[i][3] + bb[3], 0.f);
    *((float4*)(C + (size_t)r * HDIM + bn + tc * 4)) = o;
  }
}

// ---------------- GEMM2: [M,256]x[256,32] (W2 fully in LDS) ----------------
__global__ __launch_bounds__(256) void k_gemm2(const float* __restrict__ H1,
                                               const float* __restrict__ W2,
                                               float* __restrict__ T, int M) {
  __shared__ float Ws[HDIM * CDIM];  // 32 KB
  for (int i = threadIdx.x; i < HDIM * CDIM / 4; i += 256)
    ((float4*)Ws)[i] = ((const float4*)W2)[i];
  __syncthreads();
  int c = threadIdx.x & 31;
  int r0 = blockIdx.x * 64 + (threadIdx.x >> 5) * 8;
  for (int rr = 0; rr < 8; ++rr) {
    int r = r0 + rr;
    if (r >= M) break;
    const float* hrow = H1 + (size_t)r * HDIM;
    float acc = 0.f;
#pragma unroll
    for (int k4 = 0; k4 < HDIM / 4; ++k4) {
      float4 h = ((const float4*)hrow)[k4];
      acc = fmaf(h.x, Ws[(k4 * 4 + 0) * CDIM + c], acc);
      acc = fmaf(h.y, Ws[(k4 * 4 + 1) * CDIM + c], acc);
      acc = fmaf(h.z, Ws[(k4 * 4 + 2) * CDIM + c], acc);
      acc = fmaf(h.w, Ws[(k4 * 4 + 3) * CDIM + c], acc);
    }
    T[(size_t)r * CDIM + c] = acc;
  }
}

// ---------------- layer-2 aggregation + bias + log_softmax, half-wave/dst ----------------
__global__ __launch_bounds__(256) void k_agg2(const float* __restrict__ T,
                                              const int* __restrict__ srcs,
                                              const int* __restrict__ offs,
                                              const float* __restrict__ dinv,
                                              const float* __restrict__ b2,
                                              float* __restrict__ out, int N) {
  int row = (blockIdx.x * 256 + threadIdx.x) >> 5;
  int lane = threadIdx.x & 31;
  if (row >= N) return;
  float dd = dinv[row];
  float acc = T[(size_t)row * CDIM + lane] * dd * dd + b2[lane];  // self loop + bias
  int beg = offs[row], end = offs[row + 1];
  for (int k = beg; k < end; ++k) {
    int s = srcs[k];
    acc = fmaf(T[(size_t)s * CDIM + lane], dinv[s] * dd, acc);
  }
  // log_softmax across the 32 lanes of this row
  float m = acc;
#pragma unroll
  for (int w = 16; w >= 1; w >>= 1) m = fmaxf(m, __shfl_xor(m, w, 32));
  float e = __expf(acc - m);
  float ssum = e;
#pragma unroll
  for (int w = 16; w >= 1; w >>= 1) ssum += __shfl_xor(ssum, w, 32);
  out[(size_t)row * CDIM + lane] = acc - m - __logf(ssum);
}

extern "C" void kernel_launch(void* const* d_in, const int* in_sizes, int n_in,
                              void* d_out, int out_size, void* d_ws, size_t ws_size,
                              hipStream_t stream) {
  const float* x  = (const float*)d_in[0];
  const int*   ei = (const int*)d_in[1];
  const float* W1 = (const float*)d_in[2];
  const float* b1 = (const float*)d_in[3];
  const float* W2 = (const float*)d_in[4];
  const float* b2 = (const float*)d_in[5];
  float* out = (float*)d_out;
  int N = in_sizes[0] / F_IN;
  int E = in_sizes[1] / 2;

  // workspace layout (256B-aligned segments)
  char* base = (char*)d_ws;
  size_t o = 0;
  auto carve = [&](size_t bytes) { char* p = base + o; o += (bytes + 255) & ~(size_t)255; return p; };
  float* dinv = (float*)carve((size_t)N * 4);
  int*   offs = (int*)carve((size_t)(N + 1) * 4);
  int*   srcs = (int*)carve((size_t)E * 4);
  float* aggx = (float*)carve((size_t)N * F_IN * 4);   // reused: front = T (N*32)
  int half = (N + 1) / 2;
  float* hbuf = (float*)carve((size_t)half * HDIM * 4);
  // cnt / cursor live in hbuf (dead until GEMM1 writes it)
  int* cnt = (int*)hbuf;
  int* cursor = cnt + N;
  float* T = aggx;

  // CSR build
  k_cnt_init<<<(N + 255) / 256, 256, 0, stream>>>(cnt, N);
  k_deg_count<<<(E + 255) / 256, 256, 0, stream>>>(ei, cnt, E);
  k_dinv<<<(N + 255) / 256, 256, 0, stream>>>(cnt, dinv, N);
  k_scan<<<1, 1024, 0, stream>>>(cnt, offs, cursor, N);
  k_fill<<<(E + 255) / 256, 256, 0, stream>>>(ei, cursor, srcs, E);

  // layer 1 aggregation (gather)
  k_agg1<<<(N + 3) / 4, 256, 0, stream>>>(x, srcs, offs, dinv, aggx, N);

  // GEMMs, 2 row-chunks to halve the h buffer
  for (int c = 0; c < 2; ++c) {
    int r0 = c * half;
    int m = N - r0; if (m > half) m = half;
    if (m <= 0) break;
    dim3 g1((m + BM - 1) / BM, HDIM / BN);
    k_gemm1<<<g1, 256, 0, stream>>>(aggx + (size_t)r0 * F_IN, W1, b1, hbuf, m);
    k_gemm2<<<(m + 63) / 64, 256, 0, stream>>>(hbuf, W2, T + (size_t)r0 * CDIM, m);
  }

  // layer 2 aggregation + bias + log_softmax
  k_agg2<<<(N * 32 + 255) / 256, 256, 0, stream>>>(T, srcs, offs, dinv, b2, out, N);
}

// Round 3
// 686.126 us; speedup vs baseline: 4.6251x; 1.3090x over previous
//
#include <hip/hip_runtime.h>
#include <math.h>

#define F_IN 128
#define HDIM 256
#define CDIM 32
#define SCHUNK 1024  // scan elements per block

// ---------------- degree / norm / CSR build ----------------
__global__ void k_cnt_init(int* cnt, int N) {
  int i = blockIdx.x * blockDim.x + threadIdx.x;
  if (i < N) cnt[i] = 0;
}

__global__ void k_deg_count(const int* __restrict__ ei, int* __restrict__ cnt, int E) {
  int e = blockIdx.x * blockDim.x + threadIdx.x;
  if (e < E) atomicAdd(&cnt[ei[(size_t)E + e]], 1);
}

__global__ void k_dinv(const int* __restrict__ cnt, float* __restrict__ dinv, int N) {
  int i = blockIdx.x * blockDim.x + threadIdx.x;
  if (i < N) dinv[i] = rsqrtf((float)cnt[i] + 1.0f);  // +1 self loop
}

// phase 1: per-block partial sums over SCHUNK-element chunks
__global__ __launch_bounds__(256) void k_part(const int* __restrict__ cnt,
                                              int* __restrict__ part, int N) {
  __shared__ int red[256];
  int tid = threadIdx.x;
  int base = blockIdx.x * SCHUNK + tid * 4;
  int s = 0;
#pragma unroll
  for (int i = 0; i < 4; ++i) {
    int idx = base + i;
    if (idx < N) s += cnt[idx];
  }
  red[tid] = s;
  __syncthreads();
  for (int off = 128; off >= 1; off >>= 1) {
    if (tid < off) red[tid] += red[tid + off];
    __syncthreads();
  }
  if (tid == 0) part[blockIdx.x] = red[0];
}

// phase 2: single small block scans the partials (nb <= 1024), makes them exclusive
__global__ __launch_bounds__(1024) void k_scanpart(int* __restrict__ part,
                                                   int* __restrict__ offs,
                                                   int nb, int N, int Etot) {
  __shared__ int sh[1024];
  int tid = threadIdx.x;
  int v = (tid < nb) ? part[tid] : 0;
  sh[tid] = v;
  __syncthreads();
  for (int off = 1; off < 1024; off <<= 1) {
    int t = (tid >= off) ? sh[tid - off] : 0;
    __syncthreads();
    sh[tid] += t;
    __syncthreads();
  }
  if (tid < nb) part[tid] = sh[tid] - v;  // exclusive base per block
  if (tid == 0) offs[N] = Etot;
}

// phase 3: per-block local scan + base, writes offs and cursor
__global__ __launch_bounds__(256) void k_offs(const int* __restrict__ cnt,
                                              const int* __restrict__ part,
                                              int* __restrict__ offs,
                                              int* __restrict__ cursor, int N) {
  __shared__ int sh[256];
  int tid = threadIdx.x;
  int base = blockIdx.x * SCHUNK + tid * 4;
  int v[4];
  int s = 0;
#pragma unroll
  for (int i = 0; i < 4; ++i) {
    int idx = base + i;
    v[i] = (idx < N) ? cnt[idx] : 0;
    s += v[i];
  }
  sh[tid] = s;
  __syncthreads();
  for (int off = 1; off < 256; off <<= 1) {
    int t = (tid >= off) ? sh[tid - off] : 0;
    __syncthreads();
    sh[tid] += t;
    __syncthreads();
  }
  int run = part[blockIdx.x] + sh[tid] - s;  // exclusive
#pragma unroll
  for (int i = 0; i < 4; ++i) {
    int idx = base + i;
    if (idx < N) {
      offs[idx] = run;
      cursor[idx] = run;
      run += v[i];
    }
  }
}

__global__ void k_fill(const int* __restrict__ ei, int* __restrict__ cursor,
                       int* __restrict__ srcs, int E) {
  int e = blockIdx.x * blockDim.x + threadIdx.x;
  if (e >= E) return;
  int s = ei[e];
  int d = ei[(size_t)E + e];
  int pos = atomicAdd(&cursor[d], 1);
  srcs[pos] = s;
}

// ---------------- layer-1 aggregation: gather, one wave per dst ----------------
__global__ __launch_bounds__(256) void k_agg1(const float* __restrict__ x,
                                              const int* __restrict__ srcs,
                                              const int* __restrict__ offs,
                                              const float* __restrict__ dinv,
                                              float* __restrict__ agg, int N) {
  int row = (blockIdx.x * 256 + threadIdx.x) >> 6;  // one wave per row
  int lane = threadIdx.x & 63;
  if (row >= N) return;
  float dd = dinv[row];
  const float2* xr = (const float2*)(x + (size_t)row * F_IN);
  float2 v = xr[lane];
  float sc = dd * dd;
  float ax = v.x * sc, ay = v.y * sc;  // self loop
  int beg = offs[row], end = offs[row + 1];
  for (int k = beg; k < end; ++k) {
    int s = srcs[k];
    float nrm = dinv[s] * dd;
    float2 u = ((const float2*)(x + (size_t)s * F_IN))[lane];
    ax = fmaf(u.x, nrm, ax);
    ay = fmaf(u.y, nrm, ay);
  }
  float2 o; o.x = ax; o.y = ay;
  ((float2*)(agg + (size_t)row * F_IN))[lane] = o;
}

// ---------------- GEMM1: [M,128]x[128,256] + bias, relu ----------------
#define BM 64
#define BN 64
#define BK 32
__global__ __launch_bounds__(256) void k_gemm1(const float* __restrict__ A,
                                               const float* __restrict__ W,
                                               const float* __restrict__ bias,
                                               float* __restrict__ C, int M) {
  __shared__ float As[BM][BK + 1];
  __shared__ float Bs[BK][BN];
  int tid = threadIdx.x;
  int bm = blockIdx.x * BM;
  int bn = blockIdx.y * BN;
  int tr = tid >> 4, tc = tid & 15;
  float acc[4][4] = {{0.f}};
  for (int k0 = 0; k0 < F_IN; k0 += BK) {
#pragma unroll
    for (int i = 0; i < 2; ++i) {
      int f4 = tid + i * 256;
      int row = f4 >> 3, col4 = f4 & 7;
      float4 v = make_float4(0.f, 0.f, 0.f, 0.f);
      if (bm + row < M) v = ((const float4*)(A + (size_t)(bm + row) * F_IN + k0))[col4];
      As[row][col4 * 4 + 0] = v.x;
      As[row][col4 * 4 + 1] = v.y;
      As[row][col4 * 4 + 2] = v.z;
      As[row][col4 * 4 + 3] = v.w;
    }
#pragma unroll
    for (int i = 0; i < 2; ++i) {
      int f4 = tid + i * 256;
      int row = f4 >> 4, n4 = f4 & 15;
      float4 v = ((const float4*)(W + (size_t)(k0 + row) * HDIM + bn))[n4];
      *((float4*)&Bs[row][n4 * 4]) = v;
    }
    __syncthreads();
#pragma unroll
    for (int kk = 0; kk < BK; ++kk) {
      float a[4], b[4];
#pragma unroll
      for (int i = 0; i < 4; ++i) a[i] = As[tr * 4 + i][kk];
#pragma unroll
      for (int j = 0; j < 4; ++j) b[j] = Bs[kk][tc * 4 + j];
#pragma unroll
      for (int i = 0; i < 4; ++i)
#pragma unroll
        for (int j = 0; j < 4; ++j) acc[i][j] = fmaf(a[i], b[j], acc[i][j]);
    }
    __syncthreads();
  }
  float bb[4];
#pragma unroll
  for (int j = 0; j < 4; ++j) bb[j] = bias[bn + tc * 4 + j];
#pragma unroll
  for (int i = 0; i < 4; ++i) {
    int r = bm + tr * 4 + i;
    if (r >= M) continue;
    float4 o;
    o.x = fmaxf(acc[i][0] + bb[0], 0.f);
    o.y = fmaxf(acc[i][1] + bb[1], 0.f);
    o.z = fmaxf(acc[i][2] + bb[2], 0.f);
    o.w = fmaxf(acc[i][3] + bb[3], 0.f);
    *((float4*)(C + (size_t)r * HDIM + bn + tc * 4)) = o;
  }
}

// ---------------- GEMM2: [M,256]x[256,32] (W2 fully in LDS) ----------------
__global__ __launch_bounds__(256) void k_gemm2(const float* __restrict__ H1,
                                               const float* __restrict__ W2,
                                               float* __restrict__ T, int M) {
  __shared__ float Ws[HDIM * CDIM];  // 32 KB
  for (int i = threadIdx.x; i < HDIM * CDIM / 4; i += 256)
    ((float4*)Ws)[i] = ((const float4*)W2)[i];
  __syncthreads();
  int c = threadIdx.x & 31;
  int r0 = blockIdx.x * 64 + (threadIdx.x >> 5) * 8;
  for (int rr = 0; rr < 8; ++rr) {
    int r = r0 + rr;
    if (r >= M) break;
    const float* hrow = H1 + (size_t)r * HDIM;
    float acc = 0.f;
#pragma unroll
    for (int k4 = 0; k4 < HDIM / 4; ++k4) {
      float4 h = ((const float4*)hrow)[k4];
      acc = fmaf(h.x, Ws[(k4 * 4 + 0) * CDIM + c], acc);
      acc = fmaf(h.y, Ws[(k4 * 4 + 1) * CDIM + c], acc);
      acc = fmaf(h.z, Ws[(k4 * 4 + 2) * CDIM + c], acc);
      acc = fmaf(h.w, Ws[(k4 * 4 + 3) * CDIM + c], acc);
    }
    T[(size_t)r * CDIM + c] = acc;
  }
}

// ---------------- layer-2 aggregation + bias + log_softmax, half-wave/dst ----------------
__global__ __launch_bounds__(256) void k_agg2(const float* __restrict__ T,
                                              const int* __restrict__ srcs,
                                              const int* __restrict__ offs,
                                              const float* __restrict__ dinv,
                                              const float* __restrict__ b2,
                                              float* __restrict__ out, int N) {
  int row = (blockIdx.x * 256 + threadIdx.x) >> 5;
  int lane = threadIdx.x & 31;
  if (row >= N) return;
  float dd = dinv[row];
  float acc = T[(size_t)row * CDIM + lane] * dd * dd + b2[lane];  // self loop + bias
  int beg = offs[row], end = offs[row + 1];
  for (int k = beg; k < end; ++k) {
    int s = srcs[k];
    acc = fmaf(T[(size_t)s * CDIM + lane], dinv[s] * dd, acc);
  }
  // log_softmax across the 32 lanes of this row
  float m = acc;
#pragma unroll
  for (int w = 16; w >= 1; w >>= 1) m = fmaxf(m, __shfl_xor(m, w, 32));
  float e = __expf(acc - m);
  float ssum = e;
#pragma unroll
  for (int w = 16; w >= 1; w >>= 1) ssum += __shfl_xor(ssum, w, 32);
  out[(size_t)row * CDIM + lane] = acc - m - __logf(ssum);
}

extern "C" void kernel_launch(void* const* d_in, const int* in_sizes, int n_in,
                              void* d_out, int out_size, void* d_ws, size_t ws_size,
                              hipStream_t stream) {
  const float* x  = (const float*)d_in[0];
  const int*   ei = (const int*)d_in[1];
  const float* W1 = (const float*)d_in[2];
  const float* b1 = (const float*)d_in[3];
  const float* W2 = (const float*)d_in[4];
  const float* b2 = (const float*)d_in[5];
  float* out = (float*)d_out;
  int N = in_sizes[0] / F_IN;
  int E = in_sizes[1] / 2;

  // workspace layout (256B-aligned segments)
  char* base = (char*)d_ws;
  size_t o = 0;
  auto carve = [&](size_t bytes) { char* p = base + o; o += (bytes + 255) & ~(size_t)255; return p; };
  float* dinv = (float*)carve((size_t)N * 4);
  int*   offs = (int*)carve((size_t)(N + 1) * 4);
  int*   srcs = (int*)carve((size_t)E * 4);
  float* aggx = (float*)carve((size_t)N * F_IN * 4);   // reused: front = T (N*32)
  int half = (N + 1) / 2;
  float* hbuf = (float*)carve((size_t)half * HDIM * 4);
  // cnt / cursor / part live in hbuf (dead until GEMM1 writes it)
  int* cnt = (int*)hbuf;
  int* cursor = cnt + N;
  int* part = cursor + N;
  float* T = aggx;

  int nb = (N + SCHUNK - 1) / SCHUNK;

  // CSR build
  k_cnt_init<<<(N + 255) / 256, 256, 0, stream>>>(cnt, N);
  k_deg_count<<<(E + 255) / 256, 256, 0, stream>>>(ei, cnt, E);
  k_dinv<<<(N + 255) / 256, 256, 0, stream>>>(cnt, dinv, N);
  k_part<<<nb, 256, 0, stream>>>(cnt, part, N);
  k_scanpart<<<1, 1024, 0, stream>>>(part, offs, nb, N, E);
  k_offs<<<nb, 256, 0, stream>>>(cnt, part, offs, cursor, N);
  k_fill<<<(E + 255) / 256, 256, 0, stream>>>(ei, cursor, srcs, E);

  // layer 1 aggregation (gather)
  k_agg1<<<(N + 3) / 4, 256, 0, stream>>>(x, srcs, offs, dinv, aggx, N);

  // GEMMs, 2 row-chunks to halve the h buffer
  for (int c = 0; c < 2; ++c) {
    int r0 = c * half;
    int m = N - r0; if (m > half) m = half;
    if (m <= 0) break;
    dim3 g1((m + BM - 1) / BM, HDIM / BN);
    k_gemm1<<<g1, 256, 0, stream>>>(aggx + (size_t)r0 * F_IN, W1, b1, hbuf, m);
    k_gemm2<<<(m + 63) / 64, 256, 0, stream>>>(hbuf, W2, T + (size_t)r0 * CDIM, m);
  }

  // layer 2 aggregation + bias + log_softmax
  k_agg2<<<(N * 32 + 255) / 256, 256, 0, stream>>>(T, srcs, offs, dinv, b2, out, N);
}

// Round 4
// 523.268 us; speedup vs baseline: 6.0646x; 1.3112x over previous
//
#include <hip/hip_runtime.h>
#include <math.h>

#define F_IN 128
#define HDIM 256
#define CDIM 32
#define SCHUNK 1024

typedef __attribute__((ext_vector_type(8))) short s16x8;
typedef __attribute__((ext_vector_type(4))) float f32x4;

__device__ __forceinline__ unsigned bf16_rne(float f) {
  unsigned u = __float_as_uint(f);
  u += 0x7fffu + ((u >> 16) & 1u);
  return u >> 16;
}
__device__ __forceinline__ unsigned pack2(float lo, float hi) {
  return (bf16_rne(hi) << 16) | bf16_rne(lo);
}
__device__ __forceinline__ float bflo(unsigned u) { return __uint_as_float(u << 16); }
__device__ __forceinline__ float bfhi(unsigned u) { return __uint_as_float(u & 0xffff0000u); }

// ---------------- CSR build ----------------
__global__ void k_deg_count(const int* __restrict__ ei, int* __restrict__ cnt, int E) {
  int e = blockIdx.x * blockDim.x + threadIdx.x;
  if (e < E) atomicAdd(&cnt[ei[(size_t)E + e]], 1);
}

__global__ void k_dinv(const int* __restrict__ cnt, float* __restrict__ dinv, int N) {
  int i = blockIdx.x * blockDim.x + threadIdx.x;
  if (i < N) dinv[i] = rsqrtf((float)cnt[i] + 1.0f);
}

__global__ __launch_bounds__(256) void k_part(const int* __restrict__ cnt,
                                              int* __restrict__ part, int N) {
  __shared__ int red[256];
  int tid = threadIdx.x;
  int base = blockIdx.x * SCHUNK + tid * 4;
  int s = 0;
#pragma unroll
  for (int i = 0; i < 4; ++i) {
    int idx = base + i;
    if (idx < N) s += cnt[idx];
  }
  red[tid] = s;
  __syncthreads();
  for (int off = 128; off >= 1; off >>= 1) {
    if (tid < off) red[tid] += red[tid + off];
    __syncthreads();
  }
  if (tid == 0) part[blockIdx.x] = red[0];
}

__global__ __launch_bounds__(1024) void k_scanpart(int* __restrict__ part,
                                                   int* __restrict__ offs,
                                                   int nb, int N, int Etot) {
  __shared__ int sh[1024];
  int tid = threadIdx.x;
  int v = (tid < nb) ? part[tid] : 0;
  sh[tid] = v;
  __syncthreads();
  for (int off = 1; off < 1024; off <<= 1) {
    int t = (tid >= off) ? sh[tid - off] : 0;
    __syncthreads();
    sh[tid] += t;
    __syncthreads();
  }
  if (tid < nb) part[tid] = sh[tid] - v;
  if (tid == 0) offs[N] = Etot;
}

__global__ __launch_bounds__(256) void k_offs(const int* __restrict__ cnt,
                                              const int* __restrict__ part,
                                              int* __restrict__ offs,
                                              int* __restrict__ cursor, int N) {
  __shared__ int sh[256];
  int tid = threadIdx.x;
  int base = blockIdx.x * SCHUNK + tid * 4;
  int v[4];
  int s = 0;
#pragma unroll
  for (int i = 0; i < 4; ++i) {
    int idx = base + i;
    v[i] = (idx < N) ? cnt[idx] : 0;
    s += v[i];
  }
  sh[tid] = s;
  __syncthreads();
  for (int off = 1; off < 256; off <<= 1) {
    int t = (tid >= off) ? sh[tid - off] : 0;
    __syncthreads();
    sh[tid] += t;
    __syncthreads();
  }
  int run = part[blockIdx.x] + sh[tid] - s;
#pragma unroll
  for (int i = 0; i < 4; ++i) {
    int idx = base + i;
    if (idx < N) {
      offs[idx] = run;
      cursor[idx] = run;
      run += v[i];
    }
  }
}

__global__ void k_fill(const int* __restrict__ ei, int* __restrict__ cursor,
                       int* __restrict__ srcs, int E) {
  int e = blockIdx.x * blockDim.x + threadIdx.x;
  if (e >= E) return;
  int s = ei[e];
  int d = ei[(size_t)E + e];
  int pos = atomicAdd(&cursor[d], 1);
  srcs[pos] = s;
}

// ---------------- conversions ----------------
__global__ void k_cvt_x(const float2* __restrict__ x, unsigned* __restrict__ xh, long long n2) {
  long long i = (long long)blockIdx.x * blockDim.x + threadIdx.x;
  if (i >= n2) return;
  float2 v = x[i];
  xh[i] = pack2(v.x, v.y);
}

// W1 [128][256] -> W1t [256][128] bf16 ; W2 [256][32] -> W2t [32][256] bf16
__global__ void k_cvt_w(const float* __restrict__ W1, const float* __restrict__ W2,
                        short* __restrict__ W1t, short* __restrict__ W2t) {
  int t = blockIdx.x * blockDim.x + threadIdx.x;
  if (t < F_IN * HDIM) {
    int c = t >> 7, k = t & 127;
    W1t[t] = (short)bf16_rne(W1[k * HDIM + c]);
  } else {
    int t2 = t - F_IN * HDIM;
    if (t2 < HDIM * CDIM) {
      int n = t2 >> 8, k = t2 & 255;
      W2t[t2] = (short)bf16_rne(W2[k * CDIM + n]);
    }
  }
}

// ---------------- layer-1 aggregation: bf16 gather, one wave per dst ----------------
__global__ __launch_bounds__(256) void k_agg1(const unsigned* __restrict__ xh,
                                              const int* __restrict__ srcs,
                                              const int* __restrict__ offs,
                                              const float* __restrict__ dinv,
                                              unsigned* __restrict__ aggh, int N) {
  int row = (blockIdx.x * 256 + threadIdx.x) >> 6;
  int lane = threadIdx.x & 63;
  if (row >= N) return;
  float dd = dinv[row];
  unsigned u = xh[(size_t)row * 64 + lane];
  float sc = dd * dd;
  float ax = bflo(u) * sc, ay = bfhi(u) * sc;
  int beg = offs[row], end = offs[row + 1];
  for (int k = beg; k < end; ++k) {
    int s = srcs[k];
    float nrm = dinv[s] * dd;
    unsigned v = xh[(size_t)s * 64 + lane];
    ax = fmaf(bflo(v), nrm, ax);
    ay = fmaf(bfhi(v), nrm, ay);
  }
  aggh[(size_t)row * 64 + lane] = pack2(ax, ay);
}

// ---------------- GEMM1 MFMA: [M,128]bf16 x W1t[256][128]bf16 -> h1 bf16 (bias+relu) ----
__global__ __launch_bounds__(256) void k_gemm1(const short* __restrict__ aggh,
                                               const short* __restrict__ w1t,
                                               const float* __restrict__ b1,
                                               short* __restrict__ h1, int M) {
  int wid = threadIdx.x >> 6;
  int lane = threadIdx.x & 63;
  int row0 = blockIdx.x * 32;
  int col0 = wid * 64;
  int r = lane & 15, g = lane >> 4;

  s16x8 bfrag[4][4];
  const short* wp = w1t + (size_t)(col0 + r) * F_IN + g * 8;
#pragma unroll
  for (int cf = 0; cf < 4; ++cf)
#pragma unroll
    for (int ks = 0; ks < 4; ++ks)
      bfrag[cf][ks] = *(const s16x8*)(wp + cf * 16 * F_IN + ks * 32);

  f32x4 acc[2][4] = {};
  const short* ap = aggh + (size_t)(row0 + r) * F_IN + g * 8;
#pragma unroll
  for (int ks = 0; ks < 4; ++ks) {
    s16x8 a0 = *(const s16x8*)(ap + ks * 32);
    s16x8 a1 = *(const s16x8*)(ap + 16 * F_IN + ks * 32);
#pragma unroll
    for (int cf = 0; cf < 4; ++cf) {
      acc[0][cf] = __builtin_amdgcn_mfma_f32_16x16x32_bf16(a0, bfrag[cf][ks], acc[0][cf], 0, 0, 0);
      acc[1][cf] = __builtin_amdgcn_mfma_f32_16x16x32_bf16(a1, bfrag[cf][ks], acc[1][cf], 0, 0, 0);
    }
  }

  float bb[4];
#pragma unroll
  for (int cf = 0; cf < 4; ++cf) bb[cf] = b1[col0 + cf * 16 + r];
#pragma unroll
  for (int rf = 0; rf < 2; ++rf)
#pragma unroll
    for (int cf = 0; cf < 4; ++cf)
#pragma unroll
      for (int j = 0; j < 4; ++j) {
        int orow = row0 + rf * 16 + g * 4 + j;
        if (orow < M) {
          float v = fmaxf(acc[rf][cf][j] + bb[cf], 0.f);
          h1[(size_t)orow * HDIM + col0 + cf * 16 + r] = (short)bf16_rne(v);
        }
      }
}

// ---------------- GEMM2 MFMA: [M,256]bf16 x W2t[32][256]bf16 -> T f32 ----------------
__global__ __launch_bounds__(256) void k_gemm2(const short* __restrict__ h1,
                                               const short* __restrict__ w2t,
                                               float* __restrict__ T, int M) {
  int wid = threadIdx.x >> 6;
  int lane = threadIdx.x & 63;
  int row0 = blockIdx.x * 128 + wid * 32;
  int r = lane & 15, g = lane >> 4;

  s16x8 bfrag[2][8];
  const short* wp = w2t + (size_t)r * HDIM + g * 8;
#pragma unroll
  for (int cf = 0; cf < 2; ++cf)
#pragma unroll
    for (int ks = 0; ks < 8; ++ks)
      bfrag[cf][ks] = *(const s16x8*)(wp + cf * 16 * HDIM + ks * 32);

  f32x4 acc[2][2] = {};
  const short* ap = h1 + (size_t)(row0 + r) * HDIM + g * 8;
#pragma unroll
  for (int ks = 0; ks < 8; ++ks) {
    s16x8 a0 = *(const s16x8*)(ap + ks * 32);
    s16x8 a1 = *(const s16x8*)(ap + 16 * HDIM + ks * 32);
#pragma unroll
    for (int cf = 0; cf < 2; ++cf) {
      acc[0][cf] = __builtin_amdgcn_mfma_f32_16x16x32_bf16(a0, bfrag[cf][ks], acc[0][cf], 0, 0, 0);
      acc[1][cf] = __builtin_amdgcn_mfma_f32_16x16x32_bf16(a1, bfrag[cf][ks], acc[1][cf], 0, 0, 0);
    }
  }
#pragma unroll
  for (int rf = 0; rf < 2; ++rf)
#pragma unroll
    for (int cf = 0; cf < 2; ++cf)
#pragma unroll
      for (int j = 0; j < 4; ++j) {
        int orow = row0 + rf * 16 + g * 4 + j;
        if (orow < M) T[(size_t)orow * CDIM + cf * 16 + r] = acc[rf][cf][j];
      }
}

// ---------------- layer-2 aggregation + bias + log_softmax ----------------
__global__ __launch_bounds__(256) void k_agg2(const float* __restrict__ T,
                                              const int* __restrict__ srcs,
                                              const int* __restrict__ offs,
                                              const float* __restrict__ dinv,
                                              const float* __restrict__ b2,
                                              float* __restrict__ out, int N) {
  int row = (blockIdx.x * 256 + threadIdx.x) >> 5;
  int lane = threadIdx.x & 31;
  if (row >= N) return;
  float dd = dinv[row];
  float acc = T[(size_t)row * CDIM + lane] * dd * dd + b2[lane];
  int beg = offs[row], end = offs[row + 1];
  for (int k = beg; k < end; ++k) {
    int s = srcs[k];
    acc = fmaf(T[(size_t)s * CDIM + lane], dinv[s] * dd, acc);
  }
  float m = acc;
#pragma unroll
  for (int w = 16; w >= 1; w >>= 1) m = fmaxf(m, __shfl_xor(m, w, 32));
  float e = __expf(acc - m);
  float ssum = e;
#pragma unroll
  for (int w = 16; w >= 1; w >>= 1) ssum += __shfl_xor(ssum, w, 32);
  out[(size_t)row * CDIM + lane] = acc - m - __logf(ssum);
}

extern "C" void kernel_launch(void* const* d_in, const int* in_sizes, int n_in,
                              void* d_out, int out_size, void* d_ws, size_t ws_size,
                              hipStream_t stream) {
  const float* x  = (const float*)d_in[0];
  const int*   ei = (const int*)d_in[1];
  const float* W1 = (const float*)d_in[2];
  const float* b1 = (const float*)d_in[3];
  const float* W2 = (const float*)d_in[4];
  const float* b2 = (const float*)d_in[5];
  float* out = (float*)d_out;
  int N = in_sizes[0] / F_IN;
  int E = in_sizes[1] / 2;

  char* base = (char*)d_ws;
  size_t o = 0;
  auto carve = [&](size_t bytes) { char* p = base + o; o += (bytes + 255) & ~(size_t)255; return p; };
  float*    dinv = (float*)carve((size_t)N * 4);
  int*      offs = (int*)carve((size_t)(N + 1) * 4);
  int*      srcs = (int*)carve((size_t)E * 4);
  unsigned* xh   = (unsigned*)carve((size_t)N * 64 * 4);   // bf16 x, packed pairs
  unsigned* aggh = (unsigned*)carve((size_t)N * 64 * 4);   // bf16 aggregated x
  short*    h1   = (short*)carve((size_t)N * HDIM * 2);
  float*    T    = (float*)carve((size_t)N * CDIM * 4);
  short*    W1t  = (short*)carve((size_t)HDIM * F_IN * 2);
  short*    W2t  = (short*)carve((size_t)CDIM * HDIM * 2);
  // cnt / cursor / part live in h1 (dead until GEMM1 writes it)
  int* cnt = (int*)h1;
  int* cursor = cnt + N;
  int* part = cursor + N;

  int nb = (N + SCHUNK - 1) / SCHUNK;

  // conversions (independent of CSR)
  long long n2 = (long long)N * 64;
  k_cvt_x<<<(int)((n2 + 255) / 256), 256, 0, stream>>>((const float2*)x, xh, n2);
  k_cvt_w<<<(F_IN * HDIM + HDIM * CDIM + 255) / 256, 256, 0, stream>>>(W1, W2, W1t, W2t);

  // CSR build
  hipMemsetAsync(cnt, 0, (size_t)N * 4, stream);
  k_deg_count<<<(E + 255) / 256, 256, 0, stream>>>(ei, cnt, E);
  k_dinv<<<(N + 255) / 256, 256, 0, stream>>>(cnt, dinv, N);
  k_part<<<nb, 256, 0, stream>>>(cnt, part, N);
  k_scanpart<<<1, 1024, 0, stream>>>(part, offs, nb, N, E);
  k_offs<<<nb, 256, 0, stream>>>(cnt, part, offs, cursor, N);
  k_fill<<<(E + 255) / 256, 256, 0, stream>>>(ei, cursor, srcs, E);

  // layer 1: gather + MFMA GEMM
  k_agg1<<<(N + 3) / 4, 256, 0, stream>>>(xh, srcs, offs, dinv, aggh, N);
  k_gemm1<<<(N + 31) / 32, 256, 0, stream>>>((const short*)aggh, W1t, b1, h1, N);

  // layer 2: MFMA GEMM + gather + epilogue
  k_gemm2<<<(N + 127) / 128, 256, 0, stream>>>(h1, W2t, T, N);
  k_agg2<<<(N * 32 + 255) / 256, 256, 0, stream>>>(T, srcs, offs, dinv, b2, out, N);
}

// Round 5
// 405.889 us; speedup vs baseline: 7.8184x; 1.2892x over previous
//
#include <hip/hip_runtime.h>
#include <math.h>

#define F_IN 128
#define HDIM 256
#define CDIM 32
#define SCHUNK 1024

typedef __attribute__((ext_vector_type(8))) short s16x8;
typedef __attribute__((ext_vector_type(4))) float f32x4;

__device__ __forceinline__ unsigned bf16_rne(float f) {
  unsigned u = __float_as_uint(f);
  u += 0x7fffu + ((u >> 16) & 1u);
  return u >> 16;
}
__device__ __forceinline__ unsigned pack2(float lo, float hi) {
  return (bf16_rne(hi) << 16) | bf16_rne(lo);
}
__device__ __forceinline__ float bflo(unsigned u) { return __uint_as_float(u << 16); }
__device__ __forceinline__ float bfhi(unsigned u) { return __uint_as_float(u & 0xffff0000u); }

// ---------------- CSR build ----------------
__global__ void k_deg_count(const int* __restrict__ ei, int* __restrict__ cnt, int E) {
  int e = blockIdx.x * blockDim.x + threadIdx.x;
  if (e < E) atomicAdd(&cnt[ei[(size_t)E + e]], 1);
}

__global__ void k_dinv(const int* __restrict__ cnt, float* __restrict__ dinv, int N) {
  int i = blockIdx.x * blockDim.x + threadIdx.x;
  if (i < N) dinv[i] = rsqrtf((float)cnt[i] + 1.0f);
}

__global__ __launch_bounds__(256) void k_part(const int* __restrict__ cnt,
                                              int* __restrict__ part, int N) {
  __shared__ int red[256];
  int tid = threadIdx.x;
  int base = blockIdx.x * SCHUNK + tid * 4;
  int s = 0;
#pragma unroll
  for (int i = 0; i < 4; ++i) {
    int idx = base + i;
    if (idx < N) s += cnt[idx];
  }
  red[tid] = s;
  __syncthreads();
  for (int off = 128; off >= 1; off >>= 1) {
    if (tid < off) red[tid] += red[tid + off];
    __syncthreads();
  }
  if (tid == 0) part[blockIdx.x] = red[0];
}

__global__ __launch_bounds__(1024) void k_scanpart(int* __restrict__ part,
                                                   int* __restrict__ offs,
                                                   int nb, int N, int Etot) {
  __shared__ int sh[1024];
  int tid = threadIdx.x;
  int v = (tid < nb) ? part[tid] : 0;
  sh[tid] = v;
  __syncthreads();
  for (int off = 1; off < 1024; off <<= 1) {
    int t = (tid >= off) ? sh[tid - off] : 0;
    __syncthreads();
    sh[tid] += t;
    __syncthreads();
  }
  if (tid < nb) part[tid] = sh[tid] - v;
  if (tid == 0) offs[N] = Etot;
}

__global__ __launch_bounds__(256) void k_offs(const int* __restrict__ cnt,
                                              const int* __restrict__ part,
                                              int* __restrict__ offs,
                                              int* __restrict__ cursor, int N) {
  __shared__ int sh[256];
  int tid = threadIdx.x;
  int base = blockIdx.x * SCHUNK + tid * 4;
  int v[4];
  int s = 0;
#pragma unroll
  for (int i = 0; i < 4; ++i) {
    int idx = base + i;
    v[i] = (idx < N) ? cnt[idx] : 0;
    s += v[i];
  }
  sh[tid] = s;
  __syncthreads();
  for (int off = 1; off < 256; off <<= 1) {
    int t = (tid >= off) ? sh[tid - off] : 0;
    __syncthreads();
    sh[tid] += t;
    __syncthreads();
  }
  int run = part[blockIdx.x] + sh[tid] - s;
#pragma unroll
  for (int i = 0; i < 4; ++i) {
    int idx = base + i;
    if (idx < N) {
      offs[idx] = run;
      cursor[idx] = run;
      run += v[i];
    }
  }
}

// fill CSR with (src, dinv[src]) pairs so agg loops skip one dependent load
__global__ void k_fill(const int* __restrict__ ei, const float* __restrict__ dinv,
                       int* __restrict__ cursor, int2* __restrict__ srcs2, int E) {
  int e = blockIdx.x * blockDim.x + threadIdx.x;
  if (e >= E) return;
  int s = ei[e];
  int d = ei[(size_t)E + e];
  int pos = atomicAdd(&cursor[d], 1);
  int2 v;
  v.x = s;
  v.y = __float_as_int(dinv[s]);
  srcs2[pos] = v;
}

// ---------------- conversions ----------------
__global__ void k_cvt_x(const float2* __restrict__ x, unsigned* __restrict__ xh, long long n2) {
  long long i = (long long)blockIdx.x * blockDim.x + threadIdx.x;
  if (i >= n2) return;
  float2 v = x[i];
  xh[i] = pack2(v.x, v.y);
}

__global__ void k_cvt_w(const float* __restrict__ W1, const float* __restrict__ W2,
                        short* __restrict__ W1t, short* __restrict__ W2t) {
  int t = blockIdx.x * blockDim.x + threadIdx.x;
  if (t < F_IN * HDIM) {
    int c = t >> 7, k = t & 127;
    W1t[t] = (short)bf16_rne(W1[k * HDIM + c]);
  } else {
    int t2 = t - F_IN * HDIM;
    if (t2 < HDIM * CDIM) {
      int n = t2 >> 8, k = t2 & 255;
      W2t[t2] = (short)bf16_rne(W2[k * CDIM + n]);
    }
  }
}

// ---------------- layer-1 aggregation: full wave/row, even/odd edge halves ----------------
__global__ __launch_bounds__(256) void k_agg1(const uint2* __restrict__ xh2,
                                              const int2* __restrict__ srcs2,
                                              const int* __restrict__ offs,
                                              const float* __restrict__ dinv,
                                              uint2* __restrict__ aggh2, int N) {
  int row = (blockIdx.x * 256 + threadIdx.x) >> 6;
  int lane = threadIdx.x & 63;
  if (row >= N) return;
  int half = lane >> 5;    // 0: even edges, 1: odd edges
  int sl = lane & 31;      // 4 bf16 features per lane
  float dd = dinv[row];
  float a0 = 0.f, a1 = 0.f, a2 = 0.f, a3 = 0.f;
  if (half == 0) {  // self loop seeded in half 0
    uint2 u = xh2[(size_t)row * 32 + sl];
    float sc = dd * dd;
    a0 = bflo(u.x) * sc; a1 = bfhi(u.x) * sc;
    a2 = bflo(u.y) * sc; a3 = bfhi(u.y) * sc;
  }
  int beg = offs[row], end = offs[row + 1];
  int k = beg + half;
  for (; k + 2 < end; k += 4) {
    int2 s0 = srcs2[k];
    int2 s1 = srcs2[k + 2];
    uint2 v0 = xh2[(size_t)s0.x * 32 + sl];
    uint2 v1 = xh2[(size_t)s1.x * 32 + sl];
    float n0 = __int_as_float(s0.y) * dd;
    float n1 = __int_as_float(s1.y) * dd;
    a0 = fmaf(bflo(v0.x), n0, a0); a1 = fmaf(bfhi(v0.x), n0, a1);
    a2 = fmaf(bflo(v0.y), n0, a2); a3 = fmaf(bfhi(v0.y), n0, a3);
    a0 = fmaf(bflo(v1.x), n1, a0); a1 = fmaf(bfhi(v1.x), n1, a1);
    a2 = fmaf(bflo(v1.y), n1, a2); a3 = fmaf(bfhi(v1.y), n1, a3);
  }
  if (k < end) {
    int2 s0 = srcs2[k];
    uint2 v0 = xh2[(size_t)s0.x * 32 + sl];
    float n0 = __int_as_float(s0.y) * dd;
    a0 = fmaf(bflo(v0.x), n0, a0); a1 = fmaf(bfhi(v0.x), n0, a1);
    a2 = fmaf(bflo(v0.y), n0, a2); a3 = fmaf(bfhi(v0.y), n0, a3);
  }
  // combine halves
  a0 += __shfl_xor(a0, 32, 64);
  a1 += __shfl_xor(a1, 32, 64);
  a2 += __shfl_xor(a2, 32, 64);
  a3 += __shfl_xor(a3, 32, 64);
  if (half == 0) {
    uint2 o;
    o.x = pack2(a0, a1);
    o.y = pack2(a2, a3);
    aggh2[(size_t)row * 32 + sl] = o;
  }
}

// ---------------- GEMM1 MFMA ----------------
__global__ __launch_bounds__(256) void k_gemm1(const short* __restrict__ aggh,
                                               const short* __restrict__ w1t,
                                               const float* __restrict__ b1,
                                               short* __restrict__ h1, int M) {
  int wid = threadIdx.x >> 6;
  int lane = threadIdx.x & 63;
  int row0 = blockIdx.x * 32;
  int col0 = wid * 64;
  int r = lane & 15, g = lane >> 4;

  s16x8 bfrag[4][4];
  const short* wp = w1t + (size_t)(col0 + r) * F_IN + g * 8;
#pragma unroll
  for (int cf = 0; cf < 4; ++cf)
#pragma unroll
    for (int ks = 0; ks < 4; ++ks)
      bfrag[cf][ks] = *(const s16x8*)(wp + cf * 16 * F_IN + ks * 32);

  f32x4 acc[2][4] = {};
  const short* ap = aggh + (size_t)(row0 + r) * F_IN + g * 8;
#pragma unroll
  for (int ks = 0; ks < 4; ++ks) {
    s16x8 a0 = *(const s16x8*)(ap + ks * 32);
    s16x8 a1 = *(const s16x8*)(ap + 16 * F_IN + ks * 32);
#pragma unroll
    for (int cf = 0; cf < 4; ++cf) {
      acc[0][cf] = __builtin_amdgcn_mfma_f32_16x16x32_bf16(a0, bfrag[cf][ks], acc[0][cf], 0, 0, 0);
      acc[1][cf] = __builtin_amdgcn_mfma_f32_16x16x32_bf16(a1, bfrag[cf][ks], acc[1][cf], 0, 0, 0);
    }
  }

  float bb[4];
#pragma unroll
  for (int cf = 0; cf < 4; ++cf) bb[cf] = b1[col0 + cf * 16 + r];
#pragma unroll
  for (int rf = 0; rf < 2; ++rf)
#pragma unroll
    for (int cf = 0; cf < 4; ++cf)
#pragma unroll
      for (int j = 0; j < 4; ++j) {
        int orow = row0 + rf * 16 + g * 4 + j;
        if (orow < M) {
          float v = fmaxf(acc[rf][cf][j] + bb[cf], 0.f);
          h1[(size_t)orow * HDIM + col0 + cf * 16 + r] = (short)bf16_rne(v);
        }
      }
}

// ---------------- GEMM2 MFMA ----------------
__global__ __launch_bounds__(256) void k_gemm2(const short* __restrict__ h1,
                                               const short* __restrict__ w2t,
                                               float* __restrict__ T, int M) {
  int wid = threadIdx.x >> 6;
  int lane = threadIdx.x & 63;
  int row0 = blockIdx.x * 128 + wid * 32;
  int r = lane & 15, g = lane >> 4;

  s16x8 bfrag[2][8];
  const short* wp = w2t + (size_t)r * HDIM + g * 8;
#pragma unroll
  for (int cf = 0; cf < 2; ++cf)
#pragma unroll
    for (int ks = 0; ks < 8; ++ks)
      bfrag[cf][ks] = *(const s16x8*)(wp + cf * 16 * HDIM + ks * 32);

  f32x4 acc[2][2] = {};
  const short* ap = h1 + (size_t)(row0 + r) * HDIM + g * 8;
#pragma unroll
  for (int ks = 0; ks < 8; ++ks) {
    s16x8 a0 = *(const s16x8*)(ap + ks * 32);
    s16x8 a1 = *(const s16x8*)(ap + 16 * HDIM + ks * 32);
#pragma unroll
    for (int cf = 0; cf < 2; ++cf) {
      acc[0][cf] = __builtin_amdgcn_mfma_f32_16x16x32_bf16(a0, bfrag[cf][ks], acc[0][cf], 0, 0, 0);
      acc[1][cf] = __builtin_amdgcn_mfma_f32_16x16x32_bf16(a1, bfrag[cf][ks], acc[1][cf], 0, 0, 0);
    }
  }
#pragma unroll
  for (int rf = 0; rf < 2; ++rf)
#pragma unroll
    for (int cf = 0; cf < 2; ++cf)
#pragma unroll
      for (int j = 0; j < 4; ++j) {
        int orow = row0 + rf * 16 + g * 4 + j;
        if (orow < M) T[(size_t)orow * CDIM + cf * 16 + r] = acc[rf][cf][j];
      }
}

// ---------------- layer-2 aggregation + bias + log_softmax: full wave/row ----------------
__global__ __launch_bounds__(256) void k_agg2(const float* __restrict__ T,
                                              const int2* __restrict__ srcs2,
                                              const int* __restrict__ offs,
                                              const float* __restrict__ dinv,
                                              const float* __restrict__ b2,
                                              float* __restrict__ out, int N) {
  int row = (blockIdx.x * 256 + threadIdx.x) >> 6;
  int lane = threadIdx.x & 63;
  if (row >= N) return;
  int half = lane >> 5;
  int sl = lane & 31;
  float dd = dinv[row];
  float acc = 0.f;
  if (half == 0) acc = T[(size_t)row * CDIM + sl] * dd * dd + b2[sl];
  int beg = offs[row], end = offs[row + 1];
  int k = beg + half;
  for (; k + 2 < end; k += 4) {
    int2 s0 = srcs2[k];
    int2 s1 = srcs2[k + 2];
    float t0 = T[(size_t)s0.x * CDIM + sl];
    float t1 = T[(size_t)s1.x * CDIM + sl];
    acc = fmaf(t0, __int_as_float(s0.y) * dd, acc);
    acc = fmaf(t1, __int_as_float(s1.y) * dd, acc);
  }
  if (k < end) {
    int2 s0 = srcs2[k];
    acc = fmaf(T[(size_t)s0.x * CDIM + sl], __int_as_float(s0.y) * dd, acc);
  }
  acc += __shfl_xor(acc, 32, 64);
  // log_softmax across 32 lanes (both halves compute; half 0 writes)
  float m = acc;
#pragma unroll
  for (int w = 16; w >= 1; w >>= 1) m = fmaxf(m, __shfl_xor(m, w, 32));
  float e = __expf(acc - m);
  float ssum = e;
#pragma unroll
  for (int w = 16; w >= 1; w >>= 1) ssum += __shfl_xor(ssum, w, 32);
  if (half == 0) out[(size_t)row * CDIM + sl] = acc - m - __logf(ssum);
}

extern "C" void kernel_launch(void* const* d_in, const int* in_sizes, int n_in,
                              void* d_out, int out_size, void* d_ws, size_t ws_size,
                              hipStream_t stream) {
  const float* x  = (const float*)d_in[0];
  const int*   ei = (const int*)d_in[1];
  const float* W1 = (const float*)d_in[2];
  const float* b1 = (const float*)d_in[3];
  const float* W2 = (const float*)d_in[4];
  const float* b2 = (const float*)d_in[5];
  float* out = (float*)d_out;
  int N = in_sizes[0] / F_IN;
  int E = in_sizes[1] / 2;

  char* base = (char*)d_ws;
  size_t o = 0;
  auto carve = [&](size_t bytes) { char* p = base + o; o += (bytes + 255) & ~(size_t)255; return p; };
  float*    dinv  = (float*)carve((size_t)N * 4);
  int*      offs  = (int*)carve((size_t)(N + 1) * 4);
  int2*     srcs2 = (int2*)carve((size_t)E * 8);
  unsigned* xh    = (unsigned*)carve((size_t)N * 64 * 4);
  unsigned* aggh  = (unsigned*)carve((size_t)N * 64 * 4);
  short*    h1    = (short*)carve((size_t)N * HDIM * 2);
  float*    T     = (float*)carve((size_t)N * CDIM * 4);
  short*    W1t   = (short*)carve((size_t)HDIM * F_IN * 2);
  short*    W2t   = (short*)carve((size_t)CDIM * HDIM * 2);
  int* cnt = (int*)h1;       // dead until GEMM1 writes h1
  int* cursor = cnt + N;
  int* part = cursor + N;

  int nb = (N + SCHUNK - 1) / SCHUNK;

  long long n2 = (long long)N * 64;
  k_cvt_x<<<(int)((n2 + 255) / 256), 256, 0, stream>>>((const float2*)x, xh, n2);
  k_cvt_w<<<(F_IN * HDIM + HDIM * CDIM + 255) / 256, 256, 0, stream>>>(W1, W2, W1t, W2t);

  hipMemsetAsync(cnt, 0, (size_t)N * 4, stream);
  k_deg_count<<<(E + 255) / 256, 256, 0, stream>>>(ei, cnt, E);
  k_dinv<<<(N + 255) / 256, 256, 0, stream>>>(cnt, dinv, N);
  k_part<<<nb, 256, 0, stream>>>(cnt, part, N);
  k_scanpart<<<1, 1024, 0, stream>>>(part, offs, nb, N, E);
  k_offs<<<nb, 256, 0, stream>>>(cnt, part, offs, cursor, N);
  k_fill<<<(E + 255) / 256, 256, 0, stream>>>(ei, dinv, cursor, srcs2, E);

  k_agg1<<<(N + 3) / 4, 256, 0, stream>>>((const uint2*)xh, srcs2, offs, dinv, (uint2*)aggh, N);
  k_gemm1<<<(N + 31) / 32, 256, 0, stream>>>((const short*)aggh, W1t, b1, h1, N);

  k_gemm2<<<(N + 127) / 128, 256, 0, stream>>>(h1, W2t, T, N);
  k_agg2<<<(N + 3) / 4, 256, 0, stream>>>(T, srcs2, offs, dinv, b2, out, N);
}